// Round 9
// baseline (445.998 us; speedup 1.0000x reference)
//
#include <hip/hip_runtime.h>
#include <hip/hip_bf16.h>

#define DDIM 256
#define NROWS 8192
#define LOG2E5 7.2134752044448170f   // 5 / ln(2): exp(5x) = exp2(LOG2E5 * x)

typedef __attribute__((ext_vector_type(8))) __bf16 bf16x8;
typedef __attribute__((ext_vector_type(4))) float floatx4;

// async global->LDS, 16B per lane; LDS dest = wave-uniform base + lane*16.
__device__ __forceinline__ void async16(const void* g, void* l) {
    __builtin_amdgcn_global_load_lds(
        (const __attribute__((address_space(1))) unsigned int*)g,
        (__attribute__((address_space(3))) unsigned int*)l,
        16, 0, 0);
}

// Fragment-order layout (verified R5): 16-row group Rg (rows 16Rg + m),
// k-granule G (k = 32G + q*8 + j), lane (m = lane&15, q = lane>>4) owns
// 8 bf16 at byte offset (Rg*8 + G)*1024 + lane*16. A wave's fragment load
// or stage is one contiguous 1 KB block.

// Kernel 1: normalize 16 rows per block, write Af/Pf in fragment order,
// pos_sim fp32 exact, zero rowsum/out/counter. (Verbatim from R5, verified.)
__global__ __launch_bounds__(256) void normalize_repack(
    const float* __restrict__ U, const float* __restrict__ P,
    unsigned short* __restrict__ Af, unsigned short* __restrict__ Pf,
    float* __restrict__ possim, float* __restrict__ rowsum,
    float* __restrict__ out, int* __restrict__ counter)
{
    __shared__ unsigned short Ut[16 * 264];
    __shared__ unsigned short Pt[16 * 264];
    const int tid = threadIdx.x;
    const int Rg  = blockIdx.x;            // 0..511
    const int r16 = tid >> 4;
    const int c   = tid & 15;
    const int row = Rg * 16 + r16;

    if (Rg == 0 && tid == 0) { out[0] = 0.0f; counter[0] = 0; }
    if (c == 0) rowsum[row] = 0.0f;

    float4 u4[4], p4[4];
    float su = 0.0f, sp = 0.0f, up = 0.0f;
    #pragma unroll
    for (int j = 0; j < 4; ++j) {
        const size_t base = (size_t)row * DDIM + c * 16 + j * 4;
        u4[j] = *(const float4*)(U + base);
        p4[j] = *(const float4*)(P + base);
        su += u4[j].x*u4[j].x + u4[j].y*u4[j].y + u4[j].z*u4[j].z + u4[j].w*u4[j].w;
        sp += p4[j].x*p4[j].x + p4[j].y*p4[j].y + p4[j].z*p4[j].z + p4[j].w*p4[j].w;
        up += u4[j].x*p4[j].x + u4[j].y*p4[j].y + u4[j].z*p4[j].z + u4[j].w*p4[j].w;
    }
    #pragma unroll
    for (int d = 1; d < 16; d <<= 1) {
        su += __shfl_xor(su, d);
        sp += __shfl_xor(sp, d);
        up += __shfl_xor(up, d);
    }
    const float iu = rsqrtf(fmaxf(su, 1e-24f));
    const float ip = rsqrtf(fmaxf(sp, 1e-24f));
    if (c == 0) possim[row] = up * iu * ip;

    #pragma unroll
    for (int j = 0; j < 4; ++j) {
        union { ushort4 s4; __hip_bfloat16 h[4]; } cu, cp;
        cu.h[0] = __float2bfloat16(u4[j].x * iu); cu.h[1] = __float2bfloat16(u4[j].y * iu);
        cu.h[2] = __float2bfloat16(u4[j].z * iu); cu.h[3] = __float2bfloat16(u4[j].w * iu);
        cp.h[0] = __float2bfloat16(p4[j].x * ip); cp.h[1] = __float2bfloat16(p4[j].y * ip);
        cp.h[2] = __float2bfloat16(p4[j].z * ip); cp.h[3] = __float2bfloat16(p4[j].w * ip);
        *(ushort4*)&Ut[r16 * 264 + c * 16 + j * 4] = cu.s4;
        *(ushort4*)&Pt[r16 * 264 + c * 16 + j * 4] = cp.s4;
    }
    __syncthreads();

    const int lane = tid & 63;
    const int wv   = tid >> 6;
    const int m = lane & 15, q = lane >> 4;
    #pragma unroll
    for (int g = 0; g < 2; ++g) {
        const int G = wv * 2 + g;
        const bf16x8 ua = *(const bf16x8*)&Ut[m * 264 + G * 32 + q * 8];
        const bf16x8 pa = *(const bf16x8*)&Pt[m * 264 + G * 32 + q * 8];
        const size_t o = ((size_t)(Rg * 8 + G) * 64 + lane) * 8;
        *(bf16x8*)(Af + o) = ua;
        *(bf16x8*)(Pf + o) = pa;
    }
}

// Kernel 2: 128x128 tile, 4 waves 2x2 (wave 64x64, 4x4 16x16x32 bf16 MFMAs,
// acc 64 VGPR). K = 256 in 4 chunks of BK=64, TRUE double-buffered LDS
// (A+B, 4 x 16 KB): chunk k+1 staged right after the barrier publishing
// chunk k, drained a full compute phase later. LDS layout = fragment order:
// staging is the identity 1 KB copy, frag reads are ds_read_b128 at
// slot*1024 + lane*16 -> zero bank conflicts, zero address math.
__global__ void sim_exp_rowsum(
    const unsigned short* __restrict__ Af,
    const unsigned short* __restrict__ Pf,
    float* __restrict__ rowsum,
    const float* __restrict__ possim,
    int* __restrict__ counter,
    float* __restrict__ out)
{
    __shared__ __align__(16) unsigned short Abuf[2][8192];  // 2 x 16 KB
    __shared__ __align__(16) unsigned short Bbuf[2][8192];  // 2 x 16 KB
    __shared__ float ws4[4];
    __shared__ int ticket_s;

    const int tid  = threadIdx.x;
    const int lane = tid & 63;
    const int wv   = tid >> 6;
    const int wr   = wv >> 1, wc = wv & 1;
    const int m = lane & 15, q = lane >> 4;

    const int oct = blockIdx.x & 7;
    const int lin = blockIdx.x >> 3;
    const int CX  = oct * 8 + (lin & 7);   // col 128-tile (XCD-local band)
    const int RY  = lin >> 3;              // row 128-tile

    // Global fragment bases (bytes): group row  RY*8+g , granule kc*2+gg.
    const unsigned char* Ag = (const unsigned char*)Af + (size_t)RY * 8 * 8192;
    const unsigned char* Bg = (const unsigned char*)Pf + (size_t)CX * 8 * 8192;
    // (group stride = 8 granules * 1024 B = 8192 B)

    // Stage chunk kc into buffer b: 16 x 1 KB blocks per operand, 4 per wave.
    auto stage = [&](int b, int kc) {
        #pragma unroll
        for (int j = 0; j < 4; ++j) {
            const int blk = wv * 4 + j;        // 0..15
            const int g   = blk >> 1;          // group 0..7
            const int gg  = blk & 1;           // granule within chunk
            const size_t go = (size_t)g * 8192 + (size_t)(kc * 2 + gg) * 1024
                            + (size_t)lane * 16;
            async16(Ag + go, &Abuf[b][blk * 512]);
            async16(Bg + go, &Bbuf[b][blk * 512]);
        }
    };

    floatx4 acc[4][4];
    #pragma unroll
    for (int t = 0; t < 4; ++t)
        #pragma unroll
        for (int u = 0; u < 4; ++u)
            acc[t][u] = {0.0f, 0.0f, 0.0f, 0.0f};

    stage(0, 0);
    __syncthreads();

    #pragma unroll
    for (int kc = 0; kc < 4; ++kc) {
        if (kc < 3) stage((kc + 1) & 1, kc + 1);   // lands during compute
        const unsigned short* Ap = Abuf[kc & 1];
        const unsigned short* Bp = Bbuf[kc & 1];
        #pragma unroll
        for (int ks = 0; ks < 2; ++ks) {
            bf16x8 a[4], b[4];
            #pragma unroll
            for (int t = 0; t < 4; ++t)
                a[t] = *(const bf16x8*)&Ap[((wr * 4 + t) * 2 + ks) * 512 + lane * 8];
            #pragma unroll
            for (int u = 0; u < 4; ++u)
                b[u] = *(const bf16x8*)&Bp[((wc * 4 + u) * 2 + ks) * 512 + lane * 8];
            #pragma unroll
            for (int t = 0; t < 4; ++t)
                #pragma unroll
                for (int u = 0; u < 4; ++u)
                    acc[t][u] = __builtin_amdgcn_mfma_f32_16x16x32_bf16(
                        a[t], b[u], acc[t][u], 0, 0, 0);
        }
        if (kc < 3) __syncthreads();   // drains chunk kc+1 loads; guards reuse
    }

    // Epilogue: C/D col = m, row = q*4 + r (+t*16). exp2, 16-lane reduce,
    // one atomic per row per wave.
    #pragma unroll
    for (int t = 0; t < 4; ++t) {
        #pragma unroll
        for (int r = 0; r < 4; ++r) {
            float s = exp2f(LOG2E5 * acc[t][0][r]) + exp2f(LOG2E5 * acc[t][1][r])
                    + exp2f(LOG2E5 * acc[t][2][r]) + exp2f(LOG2E5 * acc[t][3][r]);
            s += __shfl_xor(s, 1);
            s += __shfl_xor(s, 2);
            s += __shfl_xor(s, 4);
            s += __shfl_xor(s, 8);
            if (m == 0) {
                const int grow = RY * 128 + wr * 64 + t * 16 + q * 4 + r;
                atomicAdd(&rowsum[grow], s);
            }
        }
    }

    // Fused finalize: last block computes loss = mean(log(rowsum) - 5*possim).
    __threadfence();
    __syncthreads();
    if (tid == 0)
        ticket_s = __hip_atomic_fetch_add(counter, 1, __ATOMIC_ACQ_REL,
                                          __HIP_MEMORY_SCOPE_AGENT);
    __syncthreads();
    if (ticket_s == 4095) {
        float part = 0.0f;
        for (int idx = tid; idx < NROWS; idx += 256) {
            const float rs = __hip_atomic_load(&rowsum[idx], __ATOMIC_RELAXED,
                                               __HIP_MEMORY_SCOPE_AGENT);
            part += __logf(rs) - 5.0f * possim[idx];
        }
        #pragma unroll
        for (int d = 1; d < 64; d <<= 1) part += __shfl_xor(part, d);
        if (lane == 0) ws4[wv] = part;
        __syncthreads();
        if (tid == 0)
            out[0] = (ws4[0] + ws4[1] + ws4[2] + ws4[3]) * (1.0f / (float)NROWS);
    }
}

extern "C" void kernel_launch(void* const* d_in, const int* in_sizes, int n_in,
                              void* d_out, int out_size, void* d_ws, size_t ws_size,
                              hipStream_t stream) {
    const float* U = (const float*)d_in[0];
    const float* P = (const float*)d_in[1];
    float* out = (float*)d_out;
    char* ws = (char*)d_ws;
    // ws: Af bf16 frag-order (4 MB) | Pf (4 MB) | rowsum (32 KB) | possim (32 KB) | counter
    unsigned short* Af = (unsigned short*)ws;
    unsigned short* Pf = (unsigned short*)(ws + 4194304);
    float* rowsum = (float*)(ws + 8388608);
    float* possim = (float*)(ws + 8388608 + 32768);
    int* counter  = (int*)(ws + 8388608 + 65536);

    normalize_repack<<<NROWS / 16, 256, 0, stream>>>(U, P, Af, Pf, possim, rowsum,
                                                     out, counter);
    sim_exp_rowsum<<<4096, 256, 0, stream>>>(Af, Pf, rowsum, possim, counter, out);
}